// Round 19
// baseline (104.687 us; speedup 1.0000x reference)
//
#include <hip/hip_runtime.h>
#include <hip/hip_bf16.h>
#include <math.h>

#define C_DIM 512
#define N_DIM 2048
#define B_DIM 4
#define NGRP 32
#define GCH 16          // channels per group
#define NHEAD 8
#define HDIM 64
#define EPSV 1e-6f

using f32x4  = __attribute__((ext_vector_type(4))) float;
using bf16x8 = __attribute__((ext_vector_type(8))) short;   // 8 bf16 raw bits (4 VGPRs)

// async global->LDS, 16B per lane; LDS dest = wave-uniform base + lane*16
#define GLL16(gp, lp) __builtin_amdgcn_global_load_lds( \
    (const __attribute__((address_space(1))) unsigned int*)(gp), \
    (__attribute__((address_space(3))) unsigned int*)(lp), 16, 0, 0)

// pack high-16 (truncated bf16) of two f32s: lo16 = a, hi16 = b
#define BFPACK(a, b) __builtin_amdgcn_perm(__float_as_uint(b), __float_as_uint(a), 0x07060302u)

// raw v_exp_f32 (2^x, 1ulp) — avoids OCML range-check wrapper
#define EXP2R(x) __builtin_amdgcn_exp2f(x)

static __device__ __forceinline__ unsigned short f2bf(float f) {
    union { __hip_bfloat16 h; unsigned short u; } cv;
    cv.h = __float2bfloat16(f);
    return cv.u;
}

// ---------------------------------------------------------------------------
// gn_stats: 2 blocks per (b,group) half-slab; partial sums.
// ---------------------------------------------------------------------------
__global__ __launch_bounds__(256) void gn_stats(const float* __restrict__ x,
                                                float* __restrict__ partial) {
    const int HSZ = GCH * N_DIM / 2;        // 16384 floats per half
    int blk = blockIdx.x;                   // 0..255
    const float4* x4 = (const float4*)(x + (size_t)blk * HSZ);
    int tid = threadIdx.x;

    float s = 0.f, ss = 0.f;
    #pragma unroll
    for (int it = 0; it < HSZ / 4 / 256; ++it) {
        float4 v = x4[tid + it * 256];
        s  += v.x + v.y + v.z + v.w;
        ss += v.x * v.x + v.y * v.y + v.z * v.z + v.w * v.w;
    }
    __shared__ float rs[256], rss[256];
    rs[tid] = s; rss[tid] = ss;
    __syncthreads();
    for (int off = 128; off > 0; off >>= 1) {
        if (tid < off) { rs[tid] += rs[tid + off]; rss[tid] += rss[tid + off]; }
        __syncthreads();
    }
    if (tid == 0) {
        partial[blk * 2]     = rs[0];
        partial[blk * 2 + 1] = rss[0];
    }
}

// ---------------------------------------------------------------------------
// gn_apply_t: x [b][c][n] fp32 -> ht [(b*n)][c] bf16 (normalized, transposed).
// ---------------------------------------------------------------------------
__global__ __launch_bounds__(256) void gn_apply_t(const float* __restrict__ x,
                                                  const float* __restrict__ partial,
                                                  const float* __restrict__ gamma,
                                                  const float* __restrict__ beta,
                                                  unsigned short* __restrict__ ht) {
    __shared__ char smem[8192];     // [64 n][64 c] bf16, rows 128B, XOR-swizzled
    const float GSZI = 1.f / (GCH * N_DIM);
    int n0 = blockIdx.x * 64, c0 = blockIdx.y * 64, b = blockIdx.z;
    int tid = threadIdx.x;
    #pragma unroll
    for (int it = 0; it < 4; ++it) {
        int idx = tid + it * 256;
        int ci = idx >> 4, n4 = (idx & 15) << 2;
        int cg = c0 + ci, grp = cg >> 4;
        int bg = b * NGRP + grp;
        float s  = partial[bg * 4]     + partial[bg * 4 + 2];
        float ss = partial[bg * 4 + 1] + partial[bg * 4 + 3];
        float mean = s * GSZI;
        float var  = ss * GSZI - mean * mean;
        float rstd = rsqrtf(var + EPSV);
        float ga = gamma[cg] * rstd, be = beta[cg] - mean * ga;
        float4 v = *(const float4*)&x[((size_t)b * C_DIM + cg) * N_DIM + n0 + n4];
        float vals[4] = {v.x, v.y, v.z, v.w};
        #pragma unroll
        for (int j = 0; j < 4; ++j) {
            int nl = n4 + j;
            *(unsigned short*)(smem + nl * 128 + ((ci * 2) ^ ((nl & 7) << 4))) =
                f2bf(vals[j] * ga + be);
        }
    }
    __syncthreads();
    #pragma unroll
    for (int i = 0; i < 2; ++i) {
        int idx = tid + i * 256;       // 512 chunks = 64 rows x 8x16B
        int row = idx >> 3, ch = idx & 7;
        bf16x8 v = *(const bf16x8*)(smem + row * 128 + ((ch * 16) ^ ((row & 7) << 4)));
        *(bf16x8*)&ht[((size_t)(b * N_DIM + n0 + row)) * C_DIM + c0 + ch * 8] = v;
    }
}

// ---------------------------------------------------------------------------
// cast4: fp32 -> bf16 for the four 512x512 weights in one launch.
// ---------------------------------------------------------------------------
__global__ __launch_bounds__(256) void cast4_bf16(const float* __restrict__ s0,
                                                  const float* __restrict__ s1,
                                                  const float* __restrict__ s2,
                                                  const float* __restrict__ s3,
                                                  unsigned short* __restrict__ dst) {
    int which = blockIdx.y;
    const float* src = (which == 0) ? s0 : (which == 1) ? s1 : (which == 2) ? s2 : s3;
    size_t idx = (size_t)blockIdx.x * 256 + threadIdx.x;
    const float4* s4 = (const float4*)src;
    float4 a = s4[idx * 2], b = s4[idx * 2 + 1];
    bf16x8 o;
    o[0] = (short)f2bf(a.x); o[1] = (short)f2bf(a.y);
    o[2] = (short)f2bf(a.z); o[3] = (short)f2bf(a.w);
    o[4] = (short)f2bf(b.x); o[5] = (short)f2bf(b.y);
    o[6] = (short)f2bf(b.z); o[7] = (short)f2bf(b.w);
    *(bf16x8*)&dst[(size_t)which * 262144 + idx * 8] = o;
}

// ---------------------------------------------------------------------------
// conv_qkv v3: fused Q/K/V convs. Uniform 5-chunk/wave staging; full
// __syncthreads (drain) semantics retained — no cross-wave vmcnt race.
// ---------------------------------------------------------------------------
__global__ __launch_bounds__(512) void conv_qkv(const unsigned short* __restrict__ Wall,
                                                const float* __restrict__ q_b,
                                                const float* __restrict__ k_b,
                                                const float* __restrict__ v_b,
                                                const unsigned short* __restrict__ ht,
                                                unsigned short* __restrict__ qt,
                                                unsigned short* __restrict__ kt,
                                                unsigned short* __restrict__ vt,
                                                float escale) {
    __shared__ char smem[40960];     // Bs 16KB | As_q 8KB | As_k 8KB | As_v 8KB

    int bn0 = blockIdx.x * 128;      // flattened b*N + n
    int bo  = blockIdx.y * 64;
    int tid = threadIdx.x;
    int L = tid & 63, w = tid >> 6;
    int g = L >> 4, c = L & 15;
    int wr = w >> 2, wc = w & 3;

    f32x4 acc[3][2][2];
    #pragma unroll
    for (int w3 = 0; w3 < 3; ++w3)
        #pragma unroll
        for (int t = 0; t < 2; ++t)
            #pragma unroll
            for (int u = 0; u < 2; ++u) acc[w3][t][u] = f32x4{0.f, 0.f, 0.f, 0.f};

    int sl = (L & 7) ^ (L >> 3);     // swizzled 16B slot (row&7 == L>>3 always)

    for (int k0 = 0; k0 < C_DIM; k0 += 64) {
        #pragma unroll
        for (int i = 0; i < 5; ++i) {
            int j = w * 5 + i;           // 0..39, wave-uniform
            const unsigned short* src;
            if (j < 16) {
                int row = j * 8 + (L >> 3);
                src = ht + (size_t)(bn0 + row) * C_DIM + k0 + sl * 8;
            } else {
                int j2 = j - 16;
                int w3 = j2 >> 3, jj = j2 & 7;
                int row = jj * 8 + (L >> 3);
                src = Wall + (size_t)w3 * 262144 + (size_t)(bo + row) * C_DIM + k0 + sl * 8;
            }
            GLL16(src, smem + j * 1024);
        }
        __syncthreads();

        bf16x8 bfr[2][2];
        #pragma unroll
        for (int u = 0; u < 2; ++u) {
            int row = wc * 32 + u * 16 + c;
            #pragma unroll
            for (int ks = 0; ks < 2; ++ks)
                bfr[u][ks] = *(const bf16x8*)(smem + row * 128 +
                                              ((g * 16 + ks * 64) ^ ((row & 7) << 4)));
        }
        #pragma unroll
        for (int w3 = 0; w3 < 3; ++w3) {
            char* As = smem + 16384 + w3 * 8192;
            bf16x8 af[2][2];
            #pragma unroll
            for (int t = 0; t < 2; ++t) {
                int row = wr * 32 + t * 16 + c;
                #pragma unroll
                for (int ks = 0; ks < 2; ++ks)
                    af[t][ks] = *(const bf16x8*)(As + row * 128 +
                                                 ((g * 16 + ks * 64) ^ ((row & 7) << 4)));
            }
            #pragma unroll
            for (int ks = 0; ks < 2; ++ks)
                #pragma unroll
                for (int t = 0; t < 2; ++t)
                    #pragma unroll
                    for (int u = 0; u < 2; ++u)
                        acc[w3][t][u] = __builtin_amdgcn_mfma_f32_16x16x32_bf16(
                            af[t][ks], bfr[u][ks], acc[w3][t][u], 0, 0, 0);
        }
        __syncthreads();
    }

    int b  = bn0 >> 11;              // N_DIM = 2048
    int nb = bn0 & (N_DIM - 1);
    int hh = bo >> 6;
    int bh = b * NHEAD + hh;

    #pragma unroll
    for (int t = 0; t < 2; ++t)
        #pragma unroll
        for (int r = 0; r < 4; ++r) {
            int m = bo + wr * 32 + t * 16 + g * 4 + r;
            float bi = v_b[m];
            #pragma unroll
            for (int u = 0; u < 2; ++u) {
                int n = nb + wc * 32 + u * 16 + c;
                vt[((size_t)b * C_DIM + m) * N_DIM + n] = f2bf(acc[2][t][u][r] + bi);
            }
        }

    char* Ts = smem;                 // [128 n][64 d] swz
    #pragma unroll
    for (int pass = 0; pass < 2; ++pass) {
        const float* bias = pass ? k_b : q_b;
        float esc = pass ? 1.0f : escale;
        unsigned short* dst = pass ? kt : qt;
        __syncthreads();
        #pragma unroll
        for (int t = 0; t < 2; ++t)
            #pragma unroll
            for (int r = 0; r < 4; ++r) {
                int ml = wr * 32 + t * 16 + g * 4 + r;   // d
                float bi = bias[bo + ml];
                #pragma unroll
                for (int u = 0; u < 2; ++u) {
                    int nl = wc * 32 + u * 16 + c;       // 0..127
                    *(unsigned short*)(Ts + nl * 128 + ((ml * 2) ^ ((nl & 7) << 4))) =
                        f2bf((acc[pass][t][u][r] + bi) * esc);
                }
            }
        __syncthreads();
        #pragma unroll
        for (int i = 0; i < 2; ++i) {
            int idx = tid + i * 512;     // 1024 chunks = 128 rows x 8x16B
            int row = idx >> 3, ch = idx & 7;
            bf16x8 v = *(const bf16x8*)(Ts + row * 128 + ((ch * 16) ^ ((row & 7) << 4)));
            *(bf16x8*)&dst[((size_t)bh * N_DIM + nb + row) * HDIM + ch * 8] = v;
        }
    }
}

// ---------------------------------------------------------------------------
// conv_proj: out fp32 [b][c][n] + residual.
// R19: double-buffer with CORRECT T4 ordering — stage(k+1) -> vmcnt(6) ->
// s_barrier (every wave certified tile-k complete) -> compute(k) -> s_barrier
// (safe to overwrite buf at k+2). Last iter drains with vmcnt(0).
// ---------------------------------------------------------------------------
__global__ __launch_bounds__(256) void conv_proj(const unsigned short* __restrict__ Wb,
                                                 const float* __restrict__ bias,
                                                 const unsigned short* __restrict__ Bsrc,
                                                 const float* __restrict__ res,
                                                 float* __restrict__ outf) {
    __shared__ char smem[49152];     // 2 x (A 8KB | B 16KB)
    int bn0 = blockIdx.x * 128;
    int bo  = blockIdx.y * 64;
    int tid = threadIdx.x;
    int L = tid & 63, w = tid >> 6;
    int g = L >> 4, c = L & 15;
    int wr = w >> 1, wc = w & 1;

    f32x4 acc[2][4];
    #pragma unroll
    for (int t = 0; t < 2; ++t)
        #pragma unroll
        for (int u = 0; u < 4; ++u) acc[t][u] = f32x4{0.f, 0.f, 0.f, 0.f};

    int sl = (L & 7) ^ (L >> 3);

    // stage(k): 2 A-chunks + 4 B-chunks per wave into buf boff
    auto stage = [&](int k0, int boff) {
        #pragma unroll
        for (int i = 0; i < 2; ++i) {
            int j = w * 2 + i;
            int ra = j * 8 + (L >> 3);
            GLL16(Wb + (size_t)(bo + ra) * C_DIM + k0 + sl * 8, smem + boff + j * 1024);
        }
        #pragma unroll
        for (int i = 0; i < 4; ++i) {
            int j = w * 4 + i;
            int rb = j * 8 + (L >> 3);
            GLL16(Bsrc + (size_t)(bn0 + rb) * C_DIM + k0 + sl * 8,
                  smem + boff + 8192 + j * 1024);
        }
    };

    stage(0, 0);

    for (int k = 0; k < 8; ++k) {
        int boff = (k & 1) * 24576;
        if (k < 7) {
            stage((k + 1) * 64, (~k & 1) * 24576);
            asm volatile("s_waitcnt vmcnt(6)" ::: "memory");   // own tile-k loads done
        } else {
            asm volatile("s_waitcnt vmcnt(0)" ::: "memory");
        }
        __builtin_amdgcn_s_barrier();          // ALL waves certified tile-k complete
        asm volatile("" ::: "memory");
        __builtin_amdgcn_sched_barrier(0);

        bf16x8 af[2][2], bfr[4][2];
        #pragma unroll
        for (int t = 0; t < 2; ++t) {
            int row = wr * 32 + t * 16 + c;
            #pragma unroll
            for (int ks = 0; ks < 2; ++ks)
                af[t][ks] = *(const bf16x8*)(smem + boff + row * 128 +
                                             ((g * 16 + ks * 64) ^ ((row & 7) << 4)));
        }
        #pragma unroll
        for (int u = 0; u < 4; ++u) {
            int row = wc * 64 + u * 16 + c;
            #pragma unroll
            for (int ks = 0; ks < 2; ++ks)
                bfr[u][ks] = *(const bf16x8*)(smem + boff + 8192 + row * 128 +
                                              ((g * 16 + ks * 64) ^ ((row & 7) << 4)));
        }
        #pragma unroll
        for (int ks = 0; ks < 2; ++ks)
            #pragma unroll
            for (int t = 0; t < 2; ++t)
                #pragma unroll
                for (int u = 0; u < 4; ++u)
                    acc[t][u] = __builtin_amdgcn_mfma_f32_16x16x32_bf16(
                        af[t][ks], bfr[u][ks], acc[t][u], 0, 0, 0);

        __builtin_amdgcn_s_barrier();          // all waves done reading buf[k&1]
        asm volatile("" ::: "memory");
    }

    int b  = bn0 >> 11;
    int nb = bn0 & (N_DIM - 1);
    #pragma unroll
    for (int t = 0; t < 2; ++t)
        #pragma unroll
        for (int r = 0; r < 4; ++r) {
            int m = bo + wr * 32 + t * 16 + g * 4 + r;
            float bi = bias[m];
            #pragma unroll
            for (int u = 0; u < 4; ++u) {
                int n = nb + wc * 64 + u * 16 + c;
                size_t off = ((size_t)b * C_DIM + m) * N_DIM + n;
                outf[off] = acc[t][u][r] + bi + res[off];
            }
        }
}

// ---------------------------------------------------------------------------
// MFMA bf16 flash attention, swapped-operand form. 8 waves, QBLK=128.
// R17 structure (byte-identical, passing config): 3 K/V buffers; per step:
// softmax(i)+P -> barrier -> stage(i+2) -> vmcnt(2) -> QK(i+1) || PV(i).
// ---------------------------------------------------------------------------
__global__ __launch_bounds__(512, 4) void attn_kernel(const unsigned short* __restrict__ Qt,
                                                      const unsigned short* __restrict__ Kt,
                                                      const unsigned short* __restrict__ Vt,
                                                      unsigned short* __restrict__ at) {
    __shared__ char smem[65536];
    // [0,16K): Q staging -> P/O strips; [16K/32K/48K): buf0/1/2 (K 8K | V 8K)

    // ---- XCD-aware remap (grid = 512 linear blocks, XCD = d % 8) ----
    int d = blockIdx.x;                // 0..511 dispatch id
    int xcd = d & 7;
    int slot = d >> 3;                 // 0..63 within XCD
    int bh = xcd + 8 * (slot >> 4);    // heads {xcd, xcd+8, xcd+16, xcd+24}
    int q0 = (slot & 15) * 128;

    int b = bh >> 3, hh = bh & 7;
    int tid = threadIdx.x;
    int L = tid & 63, w = tid >> 6;        // 8 waves
    int g = L >> 4, c = L & 15;

    const unsigned short* Qh = Qt + (size_t)bh * N_DIM * HDIM;
    const unsigned short* Kh = Kt + (size_t)bh * N_DIM * HDIM;
    const unsigned short* Vh = Vt + (size_t)bh * HDIM * N_DIM;

    // ---- prologue: stage Q (16 x 1KB) + tiles 0,1 into buf0,buf1 ----
    #pragma unroll
    for (int i = 0; i < 2; ++i) {
        int j = w * 2 + i;
        int row = j * 8 + (L >> 3);        // 0..127
        int sl = (L & 7) ^ (row & 7);
        GLL16(Qh + (size_t)(q0 + row) * HDIM + sl * 8, smem + j * 1024);
    }
    int srow = w * 8 + (L >> 3);           // staging row 0..63
    int ssl  = (L & 7) ^ (srow & 7);
    GLL16(Kh + (size_t)srow * HDIM + ssl * 8,         smem + 16384 + w * 1024);
    GLL16(Vh + (size_t)srow * N_DIM + ssl * 8,        smem + 24576 + w * 1024);
    GLL16(Kh + (size_t)(64 + srow) * HDIM + ssl * 8,  smem + 32768 + w * 1024);
    GLL16(Vh + (size_t)srow * N_DIM + 64 + ssl * 8,   smem + 40960 + w * 1024);
    __syncthreads();                       // full drain: Q + tiles 0,1 ready

    // ---- hoisted addresses (buffer-relative; add boff at use) ----
    int csw = (c & 7) << 4;
    char* kb0 = smem + c * 128 + ((g * 16) ^ csw);        // K frag ks=0
    char* kb1 = smem + c * 128 + ((g * 16 + 64) ^ csw);   // K frag ks=1
    char* pb  = smem + (w * 16 + c) * 128;                // wave-private strip
    char* pw0 = pb + ((g * 8) ^ csw);
    char* pw1 = pb + ((32 + g * 8) ^ csw);
    char* pw2 = pb + ((64 + g * 8) ^ csw);
    char* pw3 = pb + ((96 + g * 8) ^ csw);
    char* pr0 = pb + ((g * 16) ^ csw);
    char* pr1 = pb + ((64 + g * 16) ^ csw);

    // Q fragments from strip region (same addresses as pr0/pr1)
    bf16x8 qf[2];
    qf[0] = *(const bf16x8*)pr0;
    qf[1] = *(const bf16x8*)pr1;

    // staging global pointers -> tile 2
    const unsigned short* kgp = Kh + (size_t)(128 + srow) * HDIM + ssl * 8;
    const unsigned short* vgp = Vh + (size_t)srow * N_DIM + 128 + ssl * 8;

    f32x4 oacc[4];
    #pragma unroll
    for (int t = 0; t < 4; ++t) oacc[t] = f32x4{0.f, 0.f, 0.f, 0.f};
    float m_r = -INFINITY, l_part = 0.f;

    // softmax on sCur -> P strip write (exp2 domain, zero-shfl steady state)
    auto smx = [&](f32x4 (&sacc)[4]) {
        float t0 = fmaxf(fmaxf(sacc[0][0], sacc[0][1]), sacc[0][2]);
        float t1 = fmaxf(fmaxf(sacc[0][3], sacc[1][0]), sacc[1][1]);
        float t2 = fmaxf(fmaxf(sacc[1][2], sacc[1][3]), sacc[2][0]);
        float t3 = fmaxf(fmaxf(sacc[2][1], sacc[2][2]), sacc[2][3]);
        float t4 = fmaxf(fmaxf(sacc[3][0], sacc[3][1]), sacc[3][2]);
        float mloc = fmaxf(fmaxf(fmaxf(t0, t1), fmaxf(t2, t3)), fmaxf(t4, sacc[3][3]));
        if (!__all(mloc - m_r <= 6.0f)) {       // rare: row max grew
            mloc = fmaxf(mloc, __shfl_xor(mloc, 16));
            mloc = fmaxf(mloc, __shfl_xor(mloc, 32));
            float mn = fmaxf(m_r, mloc);
            float fac = EXP2R(m_r - mn);
            m_r = mn;
            l_part *= fac;
            #pragma unroll
            for (int t = 0; t < 4; ++t) oacc[t] = oacc[t] * fac;
        }
        f32x4 m4 = {m_r, m_r, m_r, m_r};
        f32x4 p[4];
        #pragma unroll
        for (int t = 0; t < 4; ++t) {
            f32x4 dd = sacc[t] - m4;
            p[t][0] = EXP2R(dd[0]);
            p[t][1] = EXP2R(dd[1]);
            p[t][2] = EXP2R(dd[2]);
            p[t][3] = EXP2R(dd[3]);
        }
        f32x4 racc = (p[0] + p[1]) + (p[2] + p[3]);
        l_part += (racc[0] + racc[1]) + (racc[2] + racc[3]);

        unsigned pk[4][2];
        #pragma unroll
        for (int t = 0; t < 4; ++t) {
            pk[t][0] = BFPACK(p[t][0], p[t][1]);
            pk[t][1] = BFPACK(p[t][2], p[t][3]);
        }
        *(unsigned long long*)pw0 = (unsigned long long)pk[0][0] | ((unsigned long long)pk[0][1] << 32);
        *(unsigned long long*)pw1 = (unsigned long long)pk[1][0] | ((unsigned long long)pk[1][1] << 32);
        *(unsigned long long*)pw2 = (unsigned long long)pk[2][0] | ((unsigned long long)pk[2][1] << 32);
        *(unsigned long long*)pw3 = (unsigned long long)pk[3][0] | ((unsigned long long)pk[3][1] << 32);
    };

    // initial QK(0) from buf0
    f32x4 sA[4], sB[4];
    #pragma unroll
    for (int t = 0; t < 4; ++t) sA[t] = f32x4{0.f, 0.f, 0.f, 0.f};
    #pragma unroll
    for (int t = 0; t < 4; ++t) {
        bf16x8 kf0 = *(const bf16x8*)(kb0 + 16384 + t * 2048);
        bf16x8 kf1 = *(const bf16x8*)(kb1 + 16384 + t * 2048);
        sA[t] = __builtin_amdgcn_mfma_f32_16x16x32_bf16(kf0, qf[0], sA[t], 0, 0, 0);
        sA[t] = __builtin_amdgcn_mfma_f32_16x16x32_bf16(kf1, qf[1], sA[t], 0, 0, 0);
    }

    // step i: softmax(i) on sCur, stage(i+2) -> stoff (or -1), then
    // QK(i+1) -> sNxt (from kboff) interleaved with PV(i) (from vboff).
    auto step = [&](f32x4 (&sCur)[4], f32x4 (&sNxt)[4], int vboff, int kboff, int stoff) {
        smx(sCur);
        __builtin_amdgcn_s_barrier();
        asm volatile("" ::: "memory");
        if (stoff >= 0) {
            GLL16(kgp, smem + stoff + w * 1024);
            GLL16(vgp, smem + stoff + 8192 + w * 1024);
            kgp += 64 * HDIM;
            vgp += 64;
            asm volatile("s_waitcnt vmcnt(2)" ::: "memory");
        } else {
            asm volatile("s_waitcnt vmcnt(0)" ::: "memory");
        }
        __builtin_amdgcn_sched_barrier(0);

        __builtin_amdgcn_s_setprio(1);
        #pragma unroll
        for (int t = 0; t < 4; ++t) sNxt[t] = f32x4{0.f, 0.f, 0.f, 0.f};
        bf16x8 pf0 = *(const bf16x8*)pr0;
        bf16x8 pf1 = *(const bf16x8*)pr1;
        #pragma unroll
        for (int t = 0; t < 4; ++t) {
            bf16x8 kf0 = *(const bf16x8*)(kb0 + kboff + t * 2048);
            bf16x8 kf1 = *(const bf16x8*)(kb1 + kboff + t * 2048);
            sNxt[t] = __builtin_amdgcn_mfma_f32_16x16x32_bf16(kf0, qf[0], sNxt[t], 0, 0, 0);
            sNxt[t] = __builtin_amdgcn_mfma_f32_16x16x32_bf16(kf1, qf[1], sNxt[t], 0, 0, 0);
            bf16x8 vf0 = *(const bf16x8*)(kb0 + vboff + 8192 + t * 2048);
            bf16x8 vf1 = *(const bf16x8*)(kb1 + vboff + 8192 + t * 2048);
            oacc[t] = __builtin_amdgcn_mfma_f32_16x16x32_bf16(vf0, pf0, oacc[t], 0, 0, 0);
            oacc[t] = __builtin_amdgcn_mfma_f32_16x16x32_bf16(vf1, pf1, oacc[t], 0, 0, 0);
        }
        __builtin_amdgcn_s_setprio(0);
    };

    // buffers: tile i lives in buf[i%3]; rotation (vb,kb,st) <- (kb,st,vb)
    int vb = 16384, kb = 32768, st = 49152;
    for (int ii = 0; ii < 15; ++ii) {      // steps i = 0..29
        step(sA, sB, vb, kb, st);
        { int t_ = vb; vb = kb; kb = st; st = t_; }
        step(sB, sA, vb, kb, st);
        { int t_ = vb; vb = kb; kb = st; st = t_; }
    }
    // step i = 30: no staging (tile 32 doesn't exist)
    step(sA, sB, vb, kb, -1);
    { int t_ = vb; vb = kb; kb = st; st = t_; }
    // i = 31: final softmax + PV only (V from buf[31%3] = vb)
    {
        smx(sB);
        bf16x8 pf0 = *(const bf16x8*)pr0;
        bf16x8 pf1 = *(const bf16x8*)pr1;
        __builtin_amdgcn_s_setprio(1);
        #pragma unroll
        for (int t = 0; t < 4; ++t) {
            bf16x8 vf0 = *(const bf16x8*)(kb0 + vb + 8192 + t * 2048);
            bf16x8 vf1 = *(const bf16x8*)(kb1 + vb + 8192 + t * 2048);
            oacc[t] = __builtin_amdgcn_mfma_f32_16x16x32_bf16(vf0, pf0, oacc[t], 0, 0, 0);
            oacc[t] = __builtin_amdgcn_mfma_f32_16x16x32_bf16(vf1, pf1, oacc[t], 0, 0, 0);
        }
        __builtin_amdgcn_s_setprio(0);
    }

    // ---- deferred l reduction + epilogue (wave-private strip) ----
    float l_r = l_part;
    l_r += __shfl_xor(l_r, 16);
    l_r += __shfl_xor(l_r, 32);
    float oinv = __builtin_amdgcn_rcpf(l_r);
    {
        unsigned lo, hi;
        lo = BFPACK(oacc[0][0] * oinv, oacc[0][1] * oinv);
        hi = BFPACK(oacc[0][2] * oinv, oacc[0][3] * oinv);
        *(unsigned long long*)pw0 = (unsigned long long)lo | ((unsigned long long)hi << 32);
        lo = BFPACK(oacc[1][0] * oinv, oacc[1][1] * oinv);
        hi = BFPACK(oacc[1][2] * oinv, oacc[1][3] * oinv);
        *(unsigned long long*)pw1 = (unsigned long long)lo | ((unsigned long long)hi << 32);
        lo = BFPACK(oacc[2][0] * oinv, oacc[2][1] * oinv);
        hi = BFPACK(oacc[2][2] * oinv, oacc[2][3] * oinv);
        *(unsigned long long*)pw2 = (unsigned long long)lo | ((unsigned long long)hi << 32);
        lo = BFPACK(oacc[3][0] * oinv, oacc[3][1] * oinv);
        hi = BFPACK(oacc[3][2] * oinv, oacc[3][3] * oinv);
        *(unsigned long long*)pw3 = (unsigned long long)lo | ((unsigned long long)hi << 32);
    }
    char* wbase = smem + w * 2048;         // wave's 16 rows
    #pragma unroll
    for (int i = 0; i < 2; ++i) {
        int idx = L + i * 64;              // 128 chunks = 16 rows x 8x16B
        int row = idx >> 3, ch = idx & 7;
        bf16x8 v = *(const bf16x8*)(wbase + row * 128 + ((ch * 16) ^ ((row & 7) << 4)));
        *(bf16x8*)&at[((size_t)(b * N_DIM + q0 + w * 16 + row)) * C_DIM + hh * HDIM + ch * 8] = v;
    }
}

// ---------------------------------------------------------------------------
extern "C" void kernel_launch(void* const* d_in, const int* in_sizes, int n_in,
                              void* d_out, int out_size, void* d_ws, size_t ws_size,
                              hipStream_t stream) {
    (void)in_sizes; (void)n_in; (void)out_size; (void)ws_size;
    const float* x     = (const float*)d_in[0];
    const float* gam   = (const float*)d_in[1];
    const float* bet   = (const float*)d_in[2];
    const float* q_w   = (const float*)d_in[3];
    const float* q_b   = (const float*)d_in[4];
    const float* k_w   = (const float*)d_in[5];
    const float* k_b   = (const float*)d_in[6];
    const float* v_w   = (const float*)d_in[7];
    const float* v_b   = (const float*)d_in[8];
    const float* p_w   = (const float*)d_in[9];
    const float* p_b   = (const float*)d_in[10];
    float* out = (float*)d_out;

    const size_t MB = 1 << 20;
    char* wsb = (char*)d_ws;
    unsigned short* ht  = (unsigned short*)(wsb);              // 8 MB  [8192][512]
    unsigned short* wqb = (unsigned short*)(wsb + 8 * MB);     // 4 x 512KB contiguous (q,k,v,p)
    unsigned short* wpb = (unsigned short*)(wsb + 9 * MB + 512 * 1024);
    float*          partial = (float*)(wsb + 10 * MB);         // 2 KB
    unsigned short* qt  = (unsigned short*)(wsb + 11 * MB);    // 8 MB [bh][n][d]
    unsigned short* kt  = (unsigned short*)(wsb + 19 * MB);    // 8 MB
    unsigned short* vt  = (unsigned short*)(wsb + 27 * MB);    // 8 MB [b][c][n]
    unsigned short* at  = (unsigned short*)(wsb + 35 * MB);    // 8 MB [b][n][c]

    gn_stats<<<B_DIM * NGRP * 2, 256, 0, stream>>>(x, partial);
    gn_apply_t<<<dim3(N_DIM / 64, C_DIM / 64, B_DIM), 256, 0, stream>>>(x, partial, gam, bet, ht);

    cast4_bf16<<<dim3(128, 4), 256, 0, stream>>>(q_w, k_w, v_w, p_w, wqb);

    const float escale = 0.044194173824159216f * 1.4426950408889634f;  // scale*log2(e)
    conv_qkv<<<dim3(B_DIM * N_DIM / 128, C_DIM / 64), 512, 0, stream>>>(
        wqb, q_b, k_b, v_b, ht, qt, kt, vt, escale);

    attn_kernel<<<512, 512, 0, stream>>>(qt, kt, vt, at);

    conv_proj<<<dim3(B_DIM * N_DIM / 128, C_DIM / 64), 256, 0, stream>>>(wpb, p_b, at, x, out);
}

// Round 20
// 102.876 us; speedup vs baseline: 1.0176x; 1.0176x over previous
//
#include <hip/hip_runtime.h>
#include <hip/hip_bf16.h>
#include <math.h>

#define C_DIM 512
#define N_DIM 2048
#define B_DIM 4
#define NGRP 32
#define GCH 16          // channels per group
#define NHEAD 8
#define HDIM 64
#define EPSV 1e-6f

using f32x4  = __attribute__((ext_vector_type(4))) float;
using bf16x8 = __attribute__((ext_vector_type(8))) short;   // 8 bf16 raw bits (4 VGPRs)

// async global->LDS, 16B per lane; LDS dest = wave-uniform base + lane*16
#define GLL16(gp, lp) __builtin_amdgcn_global_load_lds( \
    (const __attribute__((address_space(1))) unsigned int*)(gp), \
    (__attribute__((address_space(3))) unsigned int*)(lp), 16, 0, 0)

// pack high-16 (truncated bf16) of two f32s: lo16 = a, hi16 = b
#define BFPACK(a, b) __builtin_amdgcn_perm(__float_as_uint(b), __float_as_uint(a), 0x07060302u)

// raw v_exp_f32 (2^x, 1ulp) — avoids OCML range-check wrapper
#define EXP2R(x) __builtin_amdgcn_exp2f(x)

static __device__ __forceinline__ unsigned short f2bf(float f) {
    union { __hip_bfloat16 h; unsigned short u; } cv;
    cv.h = __float2bfloat16(f);
    return cv.u;
}

// ---------------------------------------------------------------------------
// gn_stats: 2 blocks per (b,group) half-slab; partial sums.
// ---------------------------------------------------------------------------
__global__ __launch_bounds__(256) void gn_stats(const float* __restrict__ x,
                                                float* __restrict__ partial) {
    const int HSZ = GCH * N_DIM / 2;        // 16384 floats per half
    int blk = blockIdx.x;                   // 0..255
    const float4* x4 = (const float4*)(x + (size_t)blk * HSZ);
    int tid = threadIdx.x;

    float s = 0.f, ss = 0.f;
    #pragma unroll
    for (int it = 0; it < HSZ / 4 / 256; ++it) {
        float4 v = x4[tid + it * 256];
        s  += v.x + v.y + v.z + v.w;
        ss += v.x * v.x + v.y * v.y + v.z * v.z + v.w * v.w;
    }
    __shared__ float rs[256], rss[256];
    rs[tid] = s; rss[tid] = ss;
    __syncthreads();
    for (int off = 128; off > 0; off >>= 1) {
        if (tid < off) { rs[tid] += rs[tid + off]; rss[tid] += rss[tid + off]; }
        __syncthreads();
    }
    if (tid == 0) {
        partial[blk * 2]     = rs[0];
        partial[blk * 2 + 1] = rss[0];
    }
}

// ---------------------------------------------------------------------------
// gn_apply_t: x [b][c][n] fp32 -> ht [(b*n)][c] bf16 (normalized, transposed).
// ---------------------------------------------------------------------------
__global__ __launch_bounds__(256) void gn_apply_t(const float* __restrict__ x,
                                                  const float* __restrict__ partial,
                                                  const float* __restrict__ gamma,
                                                  const float* __restrict__ beta,
                                                  unsigned short* __restrict__ ht) {
    __shared__ char smem[8192];     // [64 n][64 c] bf16, rows 128B, XOR-swizzled
    const float GSZI = 1.f / (GCH * N_DIM);
    int n0 = blockIdx.x * 64, c0 = blockIdx.y * 64, b = blockIdx.z;
    int tid = threadIdx.x;
    #pragma unroll
    for (int it = 0; it < 4; ++it) {
        int idx = tid + it * 256;
        int ci = idx >> 4, n4 = (idx & 15) << 2;
        int cg = c0 + ci, grp = cg >> 4;
        int bg = b * NGRP + grp;
        float s  = partial[bg * 4]     + partial[bg * 4 + 2];
        float ss = partial[bg * 4 + 1] + partial[bg * 4 + 3];
        float mean = s * GSZI;
        float var  = ss * GSZI - mean * mean;
        float rstd = rsqrtf(var + EPSV);
        float ga = gamma[cg] * rstd, be = beta[cg] - mean * ga;
        float4 v = *(const float4*)&x[((size_t)b * C_DIM + cg) * N_DIM + n0 + n4];
        float vals[4] = {v.x, v.y, v.z, v.w};
        #pragma unroll
        for (int j = 0; j < 4; ++j) {
            int nl = n4 + j;
            *(unsigned short*)(smem + nl * 128 + ((ci * 2) ^ ((nl & 7) << 4))) =
                f2bf(vals[j] * ga + be);
        }
    }
    __syncthreads();
    #pragma unroll
    for (int i = 0; i < 2; ++i) {
        int idx = tid + i * 256;       // 512 chunks = 64 rows x 8x16B
        int row = idx >> 3, ch = idx & 7;
        bf16x8 v = *(const bf16x8*)(smem + row * 128 + ((ch * 16) ^ ((row & 7) << 4)));
        *(bf16x8*)&ht[((size_t)(b * N_DIM + n0 + row)) * C_DIM + c0 + ch * 8] = v;
    }
}

// ---------------------------------------------------------------------------
// cast4: fp32 -> bf16 for the four 512x512 weights in one launch.
// ---------------------------------------------------------------------------
__global__ __launch_bounds__(256) void cast4_bf16(const float* __restrict__ s0,
                                                  const float* __restrict__ s1,
                                                  const float* __restrict__ s2,
                                                  const float* __restrict__ s3,
                                                  unsigned short* __restrict__ dst) {
    int which = blockIdx.y;
    const float* src = (which == 0) ? s0 : (which == 1) ? s1 : (which == 2) ? s2 : s3;
    size_t idx = (size_t)blockIdx.x * 256 + threadIdx.x;
    const float4* s4 = (const float4*)src;
    float4 a = s4[idx * 2], b = s4[idx * 2 + 1];
    bf16x8 o;
    o[0] = (short)f2bf(a.x); o[1] = (short)f2bf(a.y);
    o[2] = (short)f2bf(a.z); o[3] = (short)f2bf(a.w);
    o[4] = (short)f2bf(b.x); o[5] = (short)f2bf(b.y);
    o[6] = (short)f2bf(b.z); o[7] = (short)f2bf(b.w);
    *(bf16x8*)&dst[(size_t)which * 262144 + idx * 8] = o;
}

// ---------------------------------------------------------------------------
// conv_qkv: fused Q/K/V convs. Uniform 5-chunk/wave staging; full
// __syncthreads (drain) semantics — no cross-wave vmcnt race.
// ---------------------------------------------------------------------------
__global__ __launch_bounds__(512) void conv_qkv(const unsigned short* __restrict__ Wall,
                                                const float* __restrict__ q_b,
                                                const float* __restrict__ k_b,
                                                const float* __restrict__ v_b,
                                                const unsigned short* __restrict__ ht,
                                                unsigned short* __restrict__ qt,
                                                unsigned short* __restrict__ kt,
                                                unsigned short* __restrict__ vt,
                                                float escale) {
    __shared__ char smem[40960];     // Bs 16KB | As_q 8KB | As_k 8KB | As_v 8KB

    int bn0 = blockIdx.x * 128;      // flattened b*N + n
    int bo  = blockIdx.y * 64;
    int tid = threadIdx.x;
    int L = tid & 63, w = tid >> 6;
    int g = L >> 4, c = L & 15;
    int wr = w >> 2, wc = w & 3;

    f32x4 acc[3][2][2];
    #pragma unroll
    for (int w3 = 0; w3 < 3; ++w3)
        #pragma unroll
        for (int t = 0; t < 2; ++t)
            #pragma unroll
            for (int u = 0; u < 2; ++u) acc[w3][t][u] = f32x4{0.f, 0.f, 0.f, 0.f};

    int sl = (L & 7) ^ (L >> 3);     // swizzled 16B slot (row&7 == L>>3 always)

    for (int k0 = 0; k0 < C_DIM; k0 += 64) {
        #pragma unroll
        for (int i = 0; i < 5; ++i) {
            int j = w * 5 + i;           // 0..39, wave-uniform
            const unsigned short* src;
            if (j < 16) {
                int row = j * 8 + (L >> 3);
                src = ht + (size_t)(bn0 + row) * C_DIM + k0 + sl * 8;
            } else {
                int j2 = j - 16;
                int w3 = j2 >> 3, jj = j2 & 7;
                int row = jj * 8 + (L >> 3);
                src = Wall + (size_t)w3 * 262144 + (size_t)(bo + row) * C_DIM + k0 + sl * 8;
            }
            GLL16(src, smem + j * 1024);
        }
        __syncthreads();

        bf16x8 bfr[2][2];
        #pragma unroll
        for (int u = 0; u < 2; ++u) {
            int row = wc * 32 + u * 16 + c;
            #pragma unroll
            for (int ks = 0; ks < 2; ++ks)
                bfr[u][ks] = *(const bf16x8*)(smem + row * 128 +
                                              ((g * 16 + ks * 64) ^ ((row & 7) << 4)));
        }
        #pragma unroll
        for (int w3 = 0; w3 < 3; ++w3) {
            char* As = smem + 16384 + w3 * 8192;
            bf16x8 af[2][2];
            #pragma unroll
            for (int t = 0; t < 2; ++t) {
                int row = wr * 32 + t * 16 + c;
                #pragma unroll
                for (int ks = 0; ks < 2; ++ks)
                    af[t][ks] = *(const bf16x8*)(As + row * 128 +
                                                 ((g * 16 + ks * 64) ^ ((row & 7) << 4)));
            }
            #pragma unroll
            for (int ks = 0; ks < 2; ++ks)
                #pragma unroll
                for (int t = 0; t < 2; ++t)
                    #pragma unroll
                    for (int u = 0; u < 2; ++u)
                        acc[w3][t][u] = __builtin_amdgcn_mfma_f32_16x16x32_bf16(
                            af[t][ks], bfr[u][ks], acc[w3][t][u], 0, 0, 0);
        }
        __syncthreads();
    }

    int b  = bn0 >> 11;              // N_DIM = 2048
    int nb = bn0 & (N_DIM - 1);
    int hh = bo >> 6;
    int bh = b * NHEAD + hh;

    #pragma unroll
    for (int t = 0; t < 2; ++t)
        #pragma unroll
        for (int r = 0; r < 4; ++r) {
            int m = bo + wr * 32 + t * 16 + g * 4 + r;
            float bi = v_b[m];
            #pragma unroll
            for (int u = 0; u < 2; ++u) {
                int n = nb + wc * 32 + u * 16 + c;
                vt[((size_t)b * C_DIM + m) * N_DIM + n] = f2bf(acc[2][t][u][r] + bi);
            }
        }

    char* Ts = smem;                 // [128 n][64 d] swz
    #pragma unroll
    for (int pass = 0; pass < 2; ++pass) {
        const float* bias = pass ? k_b : q_b;
        float esc = pass ? 1.0f : escale;
        unsigned short* dst = pass ? kt : qt;
        __syncthreads();
        #pragma unroll
        for (int t = 0; t < 2; ++t)
            #pragma unroll
            for (int r = 0; r < 4; ++r) {
                int ml = wr * 32 + t * 16 + g * 4 + r;   // d
                float bi = bias[bo + ml];
                #pragma unroll
                for (int u = 0; u < 2; ++u) {
                    int nl = wc * 32 + u * 16 + c;       // 0..127
                    *(unsigned short*)(Ts + nl * 128 + ((ml * 2) ^ ((nl & 7) << 4))) =
                        f2bf((acc[pass][t][u][r] + bi) * esc);
                }
            }
        __syncthreads();
        #pragma unroll
        for (int i = 0; i < 2; ++i) {
            int idx = tid + i * 512;     // 1024 chunks = 128 rows x 8x16B
            int row = idx >> 3, ch = idx & 7;
            bf16x8 v = *(const bf16x8*)(Ts + row * 128 + ((ch * 16) ^ ((row & 7) << 4)));
            *(bf16x8*)&dst[((size_t)bh * N_DIM + nb + row) * HDIM + ch * 8] = v;
        }
    }
}

// ---------------------------------------------------------------------------
// conv_proj: out fp32 [b][c][n] + residual. R17 simple full-drain version
// (measured best — the R19 double-buffer variant was ~3us slower).
// ---------------------------------------------------------------------------
__global__ __launch_bounds__(256) void conv_proj(const unsigned short* __restrict__ Wb,
                                                 const float* __restrict__ bias,
                                                 const unsigned short* __restrict__ Bsrc,
                                                 const float* __restrict__ res,
                                                 float* __restrict__ outf) {
    __shared__ char smem[24576];
    int bn0 = blockIdx.x * 128;
    int bo  = blockIdx.y * 64;
    int tid = threadIdx.x;
    int L = tid & 63, w = tid >> 6;
    int g = L >> 4, c = L & 15;
    int wr = w >> 1, wc = w & 1;

    f32x4 acc[2][4];
    #pragma unroll
    for (int t = 0; t < 2; ++t)
        #pragma unroll
        for (int u = 0; u < 4; ++u) acc[t][u] = f32x4{0.f, 0.f, 0.f, 0.f};

    for (int k0 = 0; k0 < C_DIM; k0 += 64) {
        #pragma unroll
        for (int i = 0; i < 2; ++i) {
            int j = w * 2 + i;
            int ra = j * 8 + (L >> 3);
            int sl = (L & 7) ^ (ra & 7);
            GLL16(Wb + (size_t)(bo + ra) * C_DIM + k0 + sl * 8, smem + j * 1024);
        }
        #pragma unroll
        for (int i = 0; i < 4; ++i) {
            int j = w * 4 + i;
            int rb = j * 8 + (L >> 3);
            int sl = (L & 7) ^ (rb & 7);
            GLL16(Bsrc + (size_t)(bn0 + rb) * C_DIM + k0 + sl * 8, smem + 8192 + j * 1024);
        }
        __syncthreads();

        bf16x8 af[2][2], bfr[4][2];
        #pragma unroll
        for (int t = 0; t < 2; ++t) {
            int row = wr * 32 + t * 16 + c;
            #pragma unroll
            for (int ks = 0; ks < 2; ++ks)
                af[t][ks] = *(const bf16x8*)(smem + row * 128 +
                                             ((g * 16 + ks * 64) ^ ((row & 7) << 4)));
        }
        #pragma unroll
        for (int u = 0; u < 4; ++u) {
            int row = wc * 64 + u * 16 + c;
            #pragma unroll
            for (int ks = 0; ks < 2; ++ks)
                bfr[u][ks] = *(const bf16x8*)(smem + 8192 + row * 128 +
                                              ((g * 16 + ks * 64) ^ ((row & 7) << 4)));
        }
        #pragma unroll
        for (int ks = 0; ks < 2; ++ks)
            #pragma unroll
            for (int t = 0; t < 2; ++t)
                #pragma unroll
                for (int u = 0; u < 4; ++u)
                    acc[t][u] = __builtin_amdgcn_mfma_f32_16x16x32_bf16(
                        af[t][ks], bfr[u][ks], acc[t][u], 0, 0, 0);
        __syncthreads();
    }

    int b  = bn0 >> 11;
    int nb = bn0 & (N_DIM - 1);
    #pragma unroll
    for (int t = 0; t < 2; ++t)
        #pragma unroll
        for (int r = 0; r < 4; ++r) {
            int m = bo + wr * 32 + t * 16 + g * 4 + r;
            float bi = bias[m];
            #pragma unroll
            for (int u = 0; u < 4; ++u) {
                int n = nb + wc * 64 + u * 16 + c;
                size_t off = ((size_t)b * C_DIM + m) * N_DIM + n;
                outf[off] = acc[t][u][r] + bi + res[off];
            }
        }
}

// ---------------------------------------------------------------------------
// MFMA bf16 flash attention, swapped-operand form. 8 waves, QBLK=128.
// R17 structure (best measured): 3 K/V buffers; per step: softmax(i)+P ->
// barrier -> stage(i+2) -> vmcnt(2) -> QK(i+1) || PV(i). EXP2R + XCD remap.
// ---------------------------------------------------------------------------
__global__ __launch_bounds__(512, 4) void attn_kernel(const unsigned short* __restrict__ Qt,
                                                      const unsigned short* __restrict__ Kt,
                                                      const unsigned short* __restrict__ Vt,
                                                      unsigned short* __restrict__ at) {
    __shared__ char smem[65536];
    // [0,16K): Q staging -> P/O strips; [16K/32K/48K): buf0/1/2 (K 8K | V 8K)

    // ---- XCD-aware remap (grid = 512 linear blocks, XCD = d % 8) ----
    int d = blockIdx.x;                // 0..511 dispatch id
    int xcd = d & 7;
    int slot = d >> 3;                 // 0..63 within XCD
    int bh = xcd + 8 * (slot >> 4);    // heads {xcd, xcd+8, xcd+16, xcd+24}
    int q0 = (slot & 15) * 128;

    int b = bh >> 3, hh = bh & 7;
    int tid = threadIdx.x;
    int L = tid & 63, w = tid >> 6;        // 8 waves
    int g = L >> 4, c = L & 15;

    const unsigned short* Qh = Qt + (size_t)bh * N_DIM * HDIM;
    const unsigned short* Kh = Kt + (size_t)bh * N_DIM * HDIM;
    const unsigned short* Vh = Vt + (size_t)bh * HDIM * N_DIM;

    // ---- prologue: stage Q (16 x 1KB) + tiles 0,1 into buf0,buf1 ----
    #pragma unroll
    for (int i = 0; i < 2; ++i) {
        int j = w * 2 + i;
        int row = j * 8 + (L >> 3);        // 0..127
        int sl = (L & 7) ^ (row & 7);
        GLL16(Qh + (size_t)(q0 + row) * HDIM + sl * 8, smem + j * 1024);
    }
    int srow = w * 8 + (L >> 3);           // staging row 0..63
    int ssl  = (L & 7) ^ (srow & 7);
    GLL16(Kh + (size_t)srow * HDIM + ssl * 8,         smem + 16384 + w * 1024);
    GLL16(Vh + (size_t)srow * N_DIM + ssl * 8,        smem + 24576 + w * 1024);
    GLL16(Kh + (size_t)(64 + srow) * HDIM + ssl * 8,  smem + 32768 + w * 1024);
    GLL16(Vh + (size_t)srow * N_DIM + 64 + ssl * 8,   smem + 40960 + w * 1024);
    __syncthreads();                       // full drain: Q + tiles 0,1 ready

    // ---- hoisted addresses (buffer-relative; add boff at use) ----
    int csw = (c & 7) << 4;
    char* kb0 = smem + c * 128 + ((g * 16) ^ csw);        // K frag ks=0
    char* kb1 = smem + c * 128 + ((g * 16 + 64) ^ csw);   // K frag ks=1
    char* pb  = smem + (w * 16 + c) * 128;                // wave-private strip
    char* pw0 = pb + ((g * 8) ^ csw);
    char* pw1 = pb + ((32 + g * 8) ^ csw);
    char* pw2 = pb + ((64 + g * 8) ^ csw);
    char* pw3 = pb + ((96 + g * 8) ^ csw);
    char* pr0 = pb + ((g * 16) ^ csw);
    char* pr1 = pb + ((64 + g * 16) ^ csw);

    // Q fragments from strip region (same addresses as pr0/pr1)
    bf16x8 qf[2];
    qf[0] = *(const bf16x8*)pr0;
    qf[1] = *(const bf16x8*)pr1;

    // staging global pointers -> tile 2
    const unsigned short* kgp = Kh + (size_t)(128 + srow) * HDIM + ssl * 8;
    const unsigned short* vgp = Vh + (size_t)srow * N_DIM + 128 + ssl * 8;

    f32x4 oacc[4];
    #pragma unroll
    for (int t = 0; t < 4; ++t) oacc[t] = f32x4{0.f, 0.f, 0.f, 0.f};
    float m_r = -INFINITY, l_part = 0.f;

    // softmax on sCur -> P strip write (exp2 domain, zero-shfl steady state)
    auto smx = [&](f32x4 (&sacc)[4]) {
        float t0 = fmaxf(fmaxf(sacc[0][0], sacc[0][1]), sacc[0][2]);
        float t1 = fmaxf(fmaxf(sacc[0][3], sacc[1][0]), sacc[1][1]);
        float t2 = fmaxf(fmaxf(sacc[1][2], sacc[1][3]), sacc[2][0]);
        float t3 = fmaxf(fmaxf(sacc[2][1], sacc[2][2]), sacc[2][3]);
        float t4 = fmaxf(fmaxf(sacc[3][0], sacc[3][1]), sacc[3][2]);
        float mloc = fmaxf(fmaxf(fmaxf(t0, t1), fmaxf(t2, t3)), fmaxf(t4, sacc[3][3]));
        if (!__all(mloc - m_r <= 6.0f)) {       // rare: row max grew
            mloc = fmaxf(mloc, __shfl_xor(mloc, 16));
            mloc = fmaxf(mloc, __shfl_xor(mloc, 32));
            float mn = fmaxf(m_r, mloc);
            float fac = EXP2R(m_r - mn);
            m_r = mn;
            l_part *= fac;
            #pragma unroll
            for (int t = 0; t < 4; ++t) oacc[t] = oacc[t] * fac;
        }
        f32x4 m4 = {m_r, m_r, m_r, m_r};
        f32x4 p[4];
        #pragma unroll
        for (int t = 0; t < 4; ++t) {
            f32x4 dd = sacc[t] - m4;
            p[t][0] = EXP2R(dd[0]);
            p[t][1] = EXP2R(dd[1]);
            p[t][2] = EXP2R(dd[2]);
            p[t][3] = EXP2R(dd[3]);
        }
        f32x4 racc = (p[0] + p[1]) + (p[2] + p[3]);
        l_part += (racc[0] + racc[1]) + (racc[2] + racc[3]);

        unsigned pk[4][2];
        #pragma unroll
        for (int t = 0; t < 4; ++t) {
            pk[t][0] = BFPACK(p[t][0], p[t][1]);
            pk[t][1] = BFPACK(p[t][2], p[t][3]);
        }
        *(unsigned long long*)pw0 = (unsigned long long)pk[0][0] | ((unsigned long long)pk[0][1] << 32);
        *(unsigned long long*)pw1 = (unsigned long long)pk[1][0] | ((unsigned long long)pk[1][1] << 32);
        *(unsigned long long*)pw2 = (unsigned long long)pk[2][0] | ((unsigned long long)pk[2][1] << 32);
        *(unsigned long long*)pw3 = (unsigned long long)pk[3][0] | ((unsigned long long)pk[3][1] << 32);
    };

    // initial QK(0) from buf0
    f32x4 sA[4], sB[4];
    #pragma unroll
    for (int t = 0; t < 4; ++t) sA[t] = f32x4{0.f, 0.f, 0.f, 0.f};
    #pragma unroll
    for (int t = 0; t < 4; ++t) {
        bf16x8 kf0 = *(const bf16x8*)(kb0 + 16384 + t * 2048);
        bf16x8 kf1 = *(const bf16x8*)(kb1 + 16384 + t * 2048);
        sA[t] = __builtin_amdgcn_mfma_f32_16x16x32_bf16(kf0, qf[0], sA[t], 0, 0, 0);
        sA[t] = __builtin_amdgcn_mfma_f32_16x16x32_bf16(kf1, qf[1], sA[t], 0, 0, 0);
    }

    // step i: softmax(i) on sCur, stage(i+2) -> stoff (or -1), then
    // QK(i+1) -> sNxt (from kboff) interleaved with PV(i) (from vboff).
    auto step = [&](f32x4 (&sCur)[4], f32x4 (&sNxt)[4], int vboff, int kboff, int stoff) {
        smx(sCur);
        __builtin_amdgcn_s_barrier();
        asm volatile("" ::: "memory");
        if (stoff >= 0) {
            GLL16(kgp, smem + stoff + w * 1024);
            GLL16(vgp, smem + stoff + 8192 + w * 1024);
            kgp += 64 * HDIM;
            vgp += 64;
            asm volatile("s_waitcnt vmcnt(2)" ::: "memory");
        } else {
            asm volatile("s_waitcnt vmcnt(0)" ::: "memory");
        }
        __builtin_amdgcn_sched_barrier(0);

        __builtin_amdgcn_s_setprio(1);
        #pragma unroll
        for (int t = 0; t < 4; ++t) sNxt[t] = f32x4{0.f, 0.f, 0.f, 0.f};
        bf16x8 pf0 = *(const bf16x8*)pr0;
        bf16x8 pf1 = *(const bf16x8*)pr1;
        #pragma unroll
        for (int t = 0; t < 4; ++t) {
            bf16x8 kf0 = *(const bf16x8*)(kb0 + kboff + t * 2048);
            bf16x8 kf1 = *(const bf16x8*)(kb1 + kboff + t * 2048);
            sNxt[t] = __builtin_amdgcn_mfma_f32_16x16x32_bf16(kf0, qf[0], sNxt[t], 0, 0, 0);
            sNxt[t] = __builtin_amdgcn_mfma_f32_16x16x32_bf16(kf1, qf[1], sNxt[t], 0, 0, 0);
            bf16x8 vf0 = *(const bf16x8*)(kb0 + vboff + 8192 + t * 2048);
            bf16x8 vf1 = *(const bf16x8*)(kb1 + vboff + 8192 + t * 2048);
            oacc[t] = __builtin_amdgcn_mfma_f32_16x16x32_bf16(vf0, pf0, oacc[t], 0, 0, 0);
            oacc[t] = __builtin_amdgcn_mfma_f32_16x16x32_bf16(vf1, pf1, oacc[t], 0, 0, 0);
        }
        __builtin_amdgcn_s_setprio(0);
    };

    // buffers: tile i lives in buf[i%3]; rotation (vb,kb,st) <- (kb,st,vb)
    int vb = 16384, kb = 32768, st = 49152;
    for (int ii = 0; ii < 15; ++ii) {      // steps i = 0..29
        step(sA, sB, vb, kb, st);
        { int t_ = vb; vb = kb; kb = st; st = t_; }
        step(sB, sA, vb, kb, st);
        { int t_ = vb; vb = kb; kb = st; st = t_; }
    }
    // step i = 30: no staging (tile 32 doesn't exist)
    step(sA, sB, vb, kb, -1);
    { int t_ = vb; vb = kb; kb = st; st = t_; }
    // i = 31: final softmax + PV only (V from buf[31%3] = vb)
    {
        smx(sB);
        bf16x8 pf0 = *(const bf16x8*)pr0;
        bf16x8 pf1 = *(const bf16x8*)pr1;
        __builtin_amdgcn_s_setprio(1);
        #pragma unroll
        for (int t = 0; t < 4; ++t) {
            bf16x8 vf0 = *(const bf16x8*)(kb0 + vb + 8192 + t * 2048);
            bf16x8 vf1 = *(const bf16x8*)(kb1 + vb + 8192 + t * 2048);
            oacc[t] = __builtin_amdgcn_mfma_f32_16x16x32_bf16(vf0, pf0, oacc[t], 0, 0, 0);
            oacc[t] = __builtin_amdgcn_mfma_f32_16x16x32_bf16(vf1, pf1, oacc[t], 0, 0, 0);
        }
        __builtin_amdgcn_s_setprio(0);
    }

    // ---- deferred l reduction + epilogue (wave-private strip) ----
    float l_r = l_part;
    l_r += __shfl_xor(l_r, 16);
    l_r += __shfl_xor(l_r, 32);
    float oinv = __builtin_amdgcn_rcpf(l_r);
    {
        unsigned lo, hi;
        lo = BFPACK(oacc[0][0] * oinv, oacc[0][1] * oinv);
        hi = BFPACK(oacc[0][2] * oinv, oacc[0][3] * oinv);
        *(unsigned long long*)pw0 = (unsigned long long)lo | ((unsigned long long)hi << 32);
        lo = BFPACK(oacc[1][0] * oinv, oacc[1][1] * oinv);
        hi = BFPACK(oacc[1][2] * oinv, oacc[1][3] * oinv);
        *(unsigned long long*)pw1 = (unsigned long long)lo | ((unsigned long long)hi << 32);
        lo = BFPACK(oacc[2][0] * oinv, oacc[2][1] * oinv);
        hi = BFPACK(oacc[2][2] * oinv, oacc[2][3] * oinv);
        *(unsigned long long*)pw2 = (unsigned long long)lo | ((unsigned long long)hi << 32);
        lo = BFPACK(oacc[3][0] * oinv, oacc[3][1] * oinv);
        hi = BFPACK(oacc[3][2] * oinv, oacc[3][3] * oinv);
        *(unsigned long long*)pw3 = (unsigned long long)lo | ((unsigned long long)hi << 32);
    }
    char* wbase = smem + w * 2048;         // wave's 16 rows
    #pragma unroll
    for (int i = 0; i < 2; ++i) {
        int idx = L + i * 64;              // 128 chunks = 16 rows x 8x16B
        int row = idx >> 3, ch = idx & 7;
        bf16x8 v = *(const bf16x8*)(wbase + row * 128 + ((ch * 16) ^ ((row & 7) << 4)));
        *(bf16x8*)&at[((size_t)(b * N_DIM + q0 + w * 16 + row)) * C_DIM + hh * HDIM + ch * 8] = v;
    }
}

// ---------------------------------------------------------------------------
extern "C" void kernel_launch(void* const* d_in, const int* in_sizes, int n_in,
                              void* d_out, int out_size, void* d_ws, size_t ws_size,
                              hipStream_t stream) {
    (void)in_sizes; (void)n_in; (void)out_size; (void)ws_size;
    const float* x     = (const float*)d_in[0];
    const float* gam   = (const float*)d_in[1];
    const float* bet   = (const float*)d_in[2];
    const float* q_w   = (const float*)d_in[3];
    const float* q_b   = (const float*)d_in[4];
    const float* k_w   = (const float*)d_in[5];
    const float* k_b   = (const float*)d_in[6];
    const float* v_w   = (const float*)d_in[7];
    const float* v_b   = (const float*)d_in[8];
    const float* p_w   = (const float*)d_in[9];
    const float* p_b   = (const float*)d_in[10];
    float* out = (float*)d_out;

    const size_t MB = 1 << 20;
    char* wsb = (char*)d_ws;
    unsigned short* ht  = (unsigned short*)(wsb);              // 8 MB  [8192][512]
    unsigned short* wqb = (unsigned short*)(wsb + 8 * MB);     // 4 x 512KB contiguous (q,k,v,p)
    unsigned short* wpb = (unsigned short*)(wsb + 9 * MB + 512 * 1024);
    float*          partial = (float*)(wsb + 10 * MB);         // 2 KB
    unsigned short* qt  = (unsigned short*)(wsb + 11 * MB);    // 8 MB [bh][n][d]
    unsigned short* kt  = (unsigned short*)(wsb + 19 * MB);    // 8 MB
    unsigned short* vt  = (unsigned short*)(wsb + 27 * MB);    // 8 MB [b][c][n]
    unsigned short* at  = (unsigned short*)(wsb + 35 * MB);    // 8 MB [b][n][c]

    gn_stats<<<B_DIM * NGRP * 2, 256, 0, stream>>>(x, partial);
    gn_apply_t<<<dim3(N_DIM / 64, C_DIM / 64, B_DIM), 256, 0, stream>>>(x, partial, gam, bet, ht);

    cast4_bf16<<<dim3(128, 4), 256, 0, stream>>>(q_w, k_w, v_w, p_w, wqb);

    const float escale = 0.044194173824159216f * 1.4426950408889634f;  // scale*log2(e)
    conv_qkv<<<dim3(B_DIM * N_DIM / 128, C_DIM / 64), 512, 0, stream>>>(
        wqb, q_b, k_b, v_b, ht, qt, kt, vt, escale);

    attn_kernel<<<512, 512, 0, stream>>>(qt, kt, vt, at);

    conv_proj<<<dim3(B_DIM * N_DIM / 128, C_DIM / 64), 256, 0, stream>>>(wpb, p_b, at, x, out);
}